// Round 7
// baseline (2991.195 us; speedup 1.0000x reference)
//
#include <hip/hip_runtime.h>
#include <hip/hip_bf16.h>
#include <hip/hip_cooperative_groups.h>
#include <cstdint>
#include <cstddef>

namespace cg = cooperative_groups;
using bf16 = __hip_bfloat16;

typedef __attribute__((ext_vector_type(8))) short s8vec;    // 8 x bf16 MFMA frag
typedef __attribute__((ext_vector_type(4))) float f4vec;    // 4 x fp32 accumulator

#define SD 4096
#define TD 64
#define ID 64
#define EHD 128
#define ED 256
#define HD 512
#define GD 2048
#define OD 128
#define F1D 256
#define F2D 64

__device__ __forceinline__ float sigmf(float x) { return 1.0f / (1.0f + __expf(-x)); }
__device__ __forceinline__ float tanh_fast(float x) { return 1.0f - 2.0f / (__expf(2.0f * x) + 1.0f); }

__device__ __forceinline__ void async16(const bf16* g, void* lds) {
    __builtin_amdgcn_global_load_lds(
        (const __attribute__((address_space(1))) void*)g,
        (__attribute__((address_space(3))) void*)lds, 16, 0, 0);
}

__device__ __forceinline__ float bfbits2f(unsigned short u) {
    union { unsigned int i; float f; } v; v.i = (unsigned int)u << 16; return v.f;
}

// lane-wise bf16 max of two uint4 (8 bf16 each); exact (result is one input)
__device__ __forceinline__ uint4 bfmax8(uint4 a, uint4 b) {
    const unsigned short* pa = (const unsigned short*)&a;
    const unsigned short* pb = (const unsigned short*)&b;
    uint4 r; unsigned short* pr = (unsigned short*)&r;
#pragma unroll
    for (int e = 0; e < 8; ++e)
        pr[e] = (bfbits2f(pa[e]) > bfbits2f(pb[e])) ? pa[e] : pb[e];
    return r;
}

// ---------------------------------------------------------------------------
// Persistent cooperative LSTM. Grid (32,16) = 512 blocks = 2 blocks/CU
// (8 waves/CU, VGPR budget <=256 -> co-residency guaranteed with margin).
// 128x128 tile, 4 waves of 64x64 quadrants (m97 layout). Wpack rows permuted
// (R4 scheme): q=p&127: wn=q>>6, gate=(q>>4)&3, lm=q&15; j=(p>>7)*32+wn*16+lm.
// Per thread the 4 ni-blocks are the 4 gates of j=(n0>>2)+wn*16+lm; cell
// update fully in registers (c never touches memory until the end).
// One grid.sync per step; maxpool is fused into the h-part A-staging
// (reads hpre rows s-1..s+1); hpre is double-buffered to kill WAR races.
// ---------------------------------------------------------------------------
__global__ __launch_bounds__(256, 2)
void lstm_persistent(const bf16* __restrict__ x2,    // [TD][SD][ED]
                     bf16* __restrict__ hpA,         // hpre buffer 0
                     bf16* __restrict__ hpB,         // hpre buffer 1 (zero-init)
                     const bf16* __restrict__ Wpack, // [GD perm][ED+HD]
                     const float* __restrict__ biasg,
                     float* __restrict__ cbuf)       // final c out
{
    cg::grid_group grid = cg::this_grid();
    __shared__ __align__(16) bf16 As[128 * 64];   // 16 KB
    __shared__ __align__(16) bf16 Bs[128 * 64];   // 16 KB

    const int tid = threadIdx.x;
    const int lane = tid & 63;
    const int w = tid >> 6;
    const int wm = w & 1, wn = w >> 1;
    const int m0 = blockIdx.x * 128, n0 = blockIdx.y * 128;
    const int lm = lane & 15, lq = lane >> 4;
    const int j = (n0 >> 2) + wn * 16 + lm;
    const float bi = biasg[n0 + wn * 64 + lm];
    const float bff = biasg[n0 + wn * 64 + 16 + lm];
    const float bg = biasg[n0 + wn * 64 + 32 + lm];
    const float bo = biasg[n0 + wn * 64 + 48 + lm];

    float c_reg[4][4];
#pragma unroll
    for (int mi = 0; mi < 4; ++mi)
#pragma unroll
        for (int r = 0; r < 4; ++r) c_reg[mi][r] = 0.f;

    for (int t = 0; t < TD; ++t) {
        const bf16* xt = x2 + (size_t)t * SD * ED;
        const bf16* hR = (t & 1) ? hpA : hpB;   // t=0 reads hpB (zeros)
        bf16* hW = (t & 1) ? hpB : hpA;

        f4vec acc[4][4];
#pragma unroll
        for (int i = 0; i < 4; ++i)
#pragma unroll
            for (int jj = 0; jj < 4; ++jj) acc[i][jj] = (f4vec){0.f, 0.f, 0.f, 0.f};

        for (int kc = 0; kc < ED + HD; kc += 64) {
            if (kc < ED) {
                // x-part: async DMA staging
#pragma unroll
                for (int it = 0; it < 4; ++it) {
                    int flat = it * 256 + tid;
                    int row = flat >> 3, colu = flat & 7;
                    const bf16* ga = xt + (size_t)(m0 + row) * ED + kc + colu * 8;
                    uint32_t off = (uint32_t)(it * 256 + (tid & ~63)) * 16u;
                    async16(ga, (char*)As + off);
                }
            } else {
                // h-part: manual staging with fused 3-tap spatial maxpool
                const int kk = kc - ED;
#pragma unroll
                for (int it = 0; it < 4; ++it) {
                    int flat = it * 256 + tid;
                    int row = flat >> 3, colu = flat & 7;
                    int s = m0 + row;
                    const bf16* base = hR + (size_t)s * HD + kk + colu * 8;
                    uint4 res = *(const uint4*)base;
                    if (s > 0)      res = bfmax8(res, *(const uint4*)(base - HD));
                    if (s < SD - 1) res = bfmax8(res, *(const uint4*)(base + HD));
                    *(uint4*)(As + flat * 8) = res;
                }
            }
            // B: Wpack staging (async DMA)
#pragma unroll
            for (int it = 0; it < 4; ++it) {
                int flat = it * 256 + tid;
                int row = flat >> 3, colu = flat & 7;
                const bf16* gb = Wpack + (size_t)(n0 + row) * (ED + HD) + kc + colu * 8;
                uint32_t off = (uint32_t)(it * 256 + (tid & ~63)) * 16u;
                async16(gb, (char*)Bs + off);
            }
            __syncthreads();
#pragma unroll
            for (int ks = 0; ks < 64; ks += 32) {
                s8vec af[4], bfr[4];
#pragma unroll
                for (int mi = 0; mi < 4; ++mi)
                    af[mi] = *(const s8vec*)(As + (wm * 64 + mi * 16 + lm) * 64 + ks + lq * 8);
#pragma unroll
                for (int ni = 0; ni < 4; ++ni)
                    bfr[ni] = *(const s8vec*)(Bs + (wn * 64 + ni * 16 + lm) * 64 + ks + lq * 8);
#pragma unroll
                for (int mi = 0; mi < 4; ++mi)
#pragma unroll
                    for (int ni = 0; ni < 4; ++ni)
                        acc[mi][ni] = __builtin_amdgcn_mfma_f32_16x16x32_bf16(af[mi], bfr[ni], acc[mi][ni], 0, 0, 0);
            }
            __syncthreads();
        }

        // epilogue: cell update in registers; un-pooled h_pre -> hW
#pragma unroll
        for (int mi = 0; mi < 4; ++mi) {
#pragma unroll
            for (int r = 0; r < 4; ++r) {
                const int row = m0 + wm * 64 + mi * 16 + lq * 4 + r;
                float gi = acc[mi][0][r] + bi;
                float gf = acc[mi][1][r] + bff;
                float gg = acc[mi][2][r] + bg;
                float go = acc[mi][3][r] + bo;
                float cn = sigmf(gf) * c_reg[mi][r] + sigmf(gi) * tanh_fast(gg);
                c_reg[mi][r] = cn;
                hW[(size_t)row * HD + j] = __float2bfloat16(sigmf(go) * tanh_fast(cn));
            }
        }
        __threadfence();
        grid.sync();
    }

    // final c -> global (h stays un-pooled in hpB; host pools it afterwards)
#pragma unroll
    for (int mi = 0; mi < 4; ++mi)
#pragma unroll
        for (int r = 0; r < 4; ++r) {
            const int row = m0 + wm * 64 + mi * 16 + lq * 4 + r;
            cbuf[(size_t)row * HD + j] = c_reg[mi][r];
        }
}

// ---------------------------------------------------------------------------
// Fallback per-step LSTM kernel (R4 structure, known-good): reads pooled h
// from hbuf, c from global; writes c_out and un-pooled hpre.
// ---------------------------------------------------------------------------
__global__ __launch_bounds__(256, 2)
void lstm_step(const bf16* __restrict__ xt, const bf16* __restrict__ hbuf,
               const bf16* __restrict__ Wpack, const float* __restrict__ biasg,
               const float* __restrict__ c_in, float* __restrict__ c_out,
               bf16* __restrict__ h_pre)
{
    __shared__ __align__(16) bf16 As[128 * 64];
    __shared__ __align__(16) bf16 Bs[128 * 64];

    const int tid = threadIdx.x;
    const int lane = tid & 63;
    const int w = tid >> 6;
    const int wm = w & 1, wn = w >> 1;
    const int m0 = blockIdx.x * 128, n0 = blockIdx.y * 128;
    const int lm = lane & 15, lq = lane >> 4;

    f4vec acc[4][4];
#pragma unroll
    for (int i = 0; i < 4; ++i)
#pragma unroll
        for (int jj = 0; jj < 4; ++jj) acc[i][jj] = (f4vec){0.f, 0.f, 0.f, 0.f};

    for (int kc = 0; kc < ED + HD; kc += 64) {
        const bf16* Ab; int Alda, kk;
        if (kc < ED) { Ab = xt;   Alda = ED; kk = kc; }
        else         { Ab = hbuf; Alda = HD; kk = kc - ED; }
#pragma unroll
        for (int it = 0; it < 4; ++it) {
            int flat = it * 256 + tid;
            int row = flat >> 3, colu = flat & 7;
            const bf16* ga = Ab + (size_t)(m0 + row) * Alda + kk + colu * 8;
            const bf16* gb = Wpack + (size_t)(n0 + row) * (ED + HD) + kc + colu * 8;
            uint32_t off = (uint32_t)(it * 256 + (tid & ~63)) * 16u;
            async16(ga, (char*)As + off);
            async16(gb, (char*)Bs + off);
        }
        __syncthreads();
#pragma unroll
        for (int ks = 0; ks < 64; ks += 32) {
            s8vec af[4], bfr[4];
#pragma unroll
            for (int mi = 0; mi < 4; ++mi)
                af[mi] = *(const s8vec*)(As + (wm * 64 + mi * 16 + lm) * 64 + ks + lq * 8);
#pragma unroll
            for (int ni = 0; ni < 4; ++ni)
                bfr[ni] = *(const s8vec*)(Bs + (wn * 64 + ni * 16 + lm) * 64 + ks + lq * 8);
#pragma unroll
            for (int mi = 0; mi < 4; ++mi)
#pragma unroll
                for (int ni = 0; ni < 4; ++ni)
                    acc[mi][ni] = __builtin_amdgcn_mfma_f32_16x16x32_bf16(af[mi], bfr[ni], acc[mi][ni], 0, 0, 0);
        }
        __syncthreads();
    }

    const int j = (n0 >> 2) + wn * 16 + lm;
    const float bi = biasg[n0 + wn * 64 + lm];
    const float bff = biasg[n0 + wn * 64 + 16 + lm];
    const float bg = biasg[n0 + wn * 64 + 32 + lm];
    const float bo = biasg[n0 + wn * 64 + 48 + lm];
#pragma unroll
    for (int mi = 0; mi < 4; ++mi) {
#pragma unroll
        for (int r = 0; r < 4; ++r) {
            const int row = m0 + wm * 64 + mi * 16 + lq * 4 + r;
            float gi = acc[mi][0][r] + bi;
            float gf = acc[mi][1][r] + bff;
            float gg = acc[mi][2][r] + bg;
            float go = acc[mi][3][r] + bo;
            float cn = sigmf(gf) * c_in[(size_t)row * HD + j] + sigmf(gi) * tanh_fast(gg);
            c_out[(size_t)row * HD + j] = cn;
            h_pre[(size_t)row * HD + j] = __float2bfloat16(sigmf(go) * tanh_fast(cn));
        }
    }
}

// ---------------------------------------------------------------------------
// Generic NT GEMM (m97 structure), 128x128 tile: embed + head.
// ---------------------------------------------------------------------------
constexpr int MODE_BF16 = 0;
constexpr int MODE_SCATTER = 2;

template <int MODE>
__global__ __launch_bounds__(256, 2)
void gemm_kernel(const bf16* __restrict__ A1, int lda1,
                 const bf16* __restrict__ B, int ldb,
                 const float* __restrict__ bias,
                 const float* __restrict__ scale,
                 int relu, void* __restrict__ Cp, int ldc,
                 int K, int ncols)
{
    __shared__ __align__(16) bf16 As[128 * 64];
    __shared__ __align__(16) bf16 Bs[128 * 64];

    const int tid = threadIdx.x;
    const int lane = tid & 63;
    const int w = tid >> 6;
    const int wm = w & 1, wn = w >> 1;
    const int m0 = blockIdx.x * 128, n0 = blockIdx.y * 128;
    const int lm = lane & 15, lq = lane >> 4;

    f4vec acc[4][4];
#pragma unroll
    for (int i = 0; i < 4; ++i)
#pragma unroll
        for (int jj = 0; jj < 4; ++jj) acc[i][jj] = (f4vec){0.f, 0.f, 0.f, 0.f};

    for (int kc = 0; kc < K; kc += 64) {
#pragma unroll
        for (int it = 0; it < 4; ++it) {
            int flat = it * 256 + tid;
            int row = flat >> 3, colu = flat & 7;
            const bf16* ga = A1 + (size_t)(m0 + row) * lda1 + kc + colu * 8;
            const bf16* gb = B + (size_t)(n0 + row) * ldb + kc + colu * 8;
            uint32_t off = (uint32_t)(it * 256 + (tid & ~63)) * 16u;
            async16(ga, (char*)As + off);
            async16(gb, (char*)Bs + off);
        }
        __syncthreads();
#pragma unroll
        for (int ks = 0; ks < 64; ks += 32) {
            s8vec af[4], bfr[4];
#pragma unroll
            for (int mi = 0; mi < 4; ++mi)
                af[mi] = *(const s8vec*)(As + (wm * 64 + mi * 16 + lm) * 64 + ks + lq * 8);
#pragma unroll
            for (int ni = 0; ni < 4; ++ni)
                bfr[ni] = *(const s8vec*)(Bs + (wn * 64 + ni * 16 + lm) * 64 + ks + lq * 8);
#pragma unroll
            for (int mi = 0; mi < 4; ++mi)
#pragma unroll
                for (int ni = 0; ni < 4; ++ni)
                    acc[mi][ni] = __builtin_amdgcn_mfma_f32_16x16x32_bf16(af[mi], bfr[ni], acc[mi][ni], 0, 0, 0);
        }
        __syncthreads();
    }

    const float sc = scale ? scale[0] : 1.0f;
#pragma unroll
    for (int mi = 0; mi < 4; ++mi) {
#pragma unroll
        for (int ni = 0; ni < 4; ++ni) {
            const int gcol = n0 + wn * 64 + ni * 16 + lm;
            const float bv = bias[gcol];
#pragma unroll
            for (int r = 0; r < 4; ++r) {
                const int grow = m0 + wm * 64 + mi * 16 + lq * 4 + r;
                float v = acc[mi][ni][r] * sc + bv;
                if (relu) v = fmaxf(v, 0.f);
                if constexpr (MODE == MODE_BF16) {
                    if (gcol < ncols)
                        ((bf16*)Cp)[(size_t)grow * ldc + gcol] = __float2bfloat16(v);
                } else {
                    const int crow = (grow & 63) * SD + (grow >> 6);
                    ((bf16*)Cp)[(size_t)crow * ldc + gcol] = __float2bfloat16(v);
                }
            }
        }
    }
}

// ---------------------------------------------------------------------------
// Prep (R4 Wpack permutation: q=p&127: wn=q>>6, gate=(q>>4)&3, lm=q&15;
// j=(p>>7)*32+wn*16+lm; orig row = gate*512+j) + all weight conversions.
// ---------------------------------------------------------------------------
__global__ void prep_kernel(const float* __restrict__ Wih, const float* __restrict__ Whh,
                            const float* __restrict__ bih, const float* __restrict__ bhh,
                            const float* __restrict__ We1, const float* __restrict__ We2,
                            const float* __restrict__ Wout, const float* __restrict__ Wf1,
                            const float* __restrict__ Wf2, const float* __restrict__ bf2,
                            bf16* __restrict__ Wpack, float* __restrict__ biasg,
                            bf16* __restrict__ We1b, bf16* __restrict__ We2b,
                            bf16* __restrict__ Woutb, bf16* __restrict__ Wf1b,
                            bf16* __restrict__ Wf2p, float* __restrict__ bf2f)
{
    int idx = blockIdx.x * 256 + threadIdx.x;
    const int S0 = GD * (ED + HD);
    if (idx < S0) {
        int p = idx / (ED + HD), k = idx - p * (ED + HD);
        int q = p & 127;
        int jv = (p >> 7) * 32 + ((q >> 6) << 4) + (q & 15);
        int gate = (q >> 4) & 3;
        int orig = gate * HD + jv;
        float v = (k < ED) ? Wih[(size_t)orig * ED + k] : Whh[(size_t)orig * HD + (k - ED)];
        Wpack[idx] = __float2bfloat16(v);
        return;
    }
    idx -= S0;
    if (idx < GD) {
        int p = idx, q = p & 127;
        int jv = (p >> 7) * 32 + ((q >> 6) << 4) + (q & 15);
        int gate = (q >> 4) & 3;
        int orig = gate * HD + jv;
        biasg[p] = bih[orig] + bhh[orig];
        return;
    }
    idx -= GD;
    if (idx < EHD * ID) { We1b[idx] = __float2bfloat16(We1[idx]); return; }
    idx -= EHD * ID;
    if (idx < ED * EHD) { We2b[idx] = __float2bfloat16(We2[idx]); return; }
    idx -= ED * EHD;
    if (idx < OD * HD) { Woutb[idx] = __float2bfloat16(Wout[idx]); return; }
    idx -= OD * HD;
    if (idx < F1D * OD) { Wf1b[idx] = __float2bfloat16(Wf1[idx]); return; }
    idx -= F1D * OD;
    if (idx < 128 * F1D) {
        int nrow = idx >> 8;
        Wf2p[idx] = (nrow < F2D) ? __float2bfloat16(Wf2[idx]) : __float2bfloat16(0.f);
        return;
    }
    idx -= 128 * F1D;
    if (idx < 128) { bf2f[idx] = (idx < F2D) ? bf2[idx] : 0.f; return; }
}

__global__ void cvt_input_kernel(const float* __restrict__ src, bf16* __restrict__ dst)
{
    int i = (blockIdx.x * 256 + threadIdx.x) * 8;
    float4 a = *(const float4*)(src + i);
    float4 b = *(const float4*)(src + i + 4);
    bf16 o[8] = { __float2bfloat16(a.x), __float2bfloat16(a.y),
                  __float2bfloat16(a.z), __float2bfloat16(a.w),
                  __float2bfloat16(b.x), __float2bfloat16(b.y),
                  __float2bfloat16(b.z), __float2bfloat16(b.w) };
    *(uint4*)(dst + i) = *(const uint4*)o;
}

__global__ void lane_kernel(const float* __restrict__ lane, const float* __restrict__ Wlg1,
                            const float* __restrict__ blg1, const float* __restrict__ Wlg2,
                            const float* __restrict__ blg2, float* __restrict__ laneC)
{
    if (threadIdx.x != 0) return;
    const float l = lane[0];
    float acc = blg2[0];
    for (int k = 0; k < 32; ++k)
        acc += fmaxf(l * Wlg1[k] + blg1[k], 0.f) * Wlg2[k];
    float v = 1.f / (1.f + __expf(-acc));
    laneC[0] = v;
    laneC[1] = 1.f / v;
}

__global__ void zero_kernel(float* __restrict__ c0, bf16* __restrict__ h,
                            bf16* __restrict__ hp)
{
    int idx = blockIdx.x * 256 + threadIdx.x;
    if (idx < SD * HD) {
        c0[idx] = 0.f;
        h[idx] = __float2bfloat16(0.f);
        hp[idx] = __float2bfloat16(0.f);
    }
}

__global__ void maxpool_kernel(const bf16* __restrict__ hp, bf16* __restrict__ hout)
{
    int base = (blockIdx.x * 256 + threadIdx.x) * 8;
    int s = base >> 9;
    uint4 res = *(const uint4*)(hp + base);
    if (s > 0)      res = bfmax8(res, *(const uint4*)(hp + base - HD));
    if (s < SD - 1) res = bfmax8(res, *(const uint4*)(hp + base + HD));
    *(uint4*)(hout + base) = res;
}

__global__ void f3_kernel(const bf16* __restrict__ xf2, const float* __restrict__ Wf3,
                          const float* __restrict__ bf3, const float* __restrict__ laneC,
                          float* __restrict__ out)
{
    int s = blockIdx.x * 256 + threadIdx.x;
    if (s >= SD) return;
    float acc = bf3[0];
#pragma unroll
    for (int k = 0; k < F2D; ++k)
        acc += __bfloat162float(xf2[(size_t)s * F2D + k]) * Wf3[k];
    out[s] = acc * laneC[1];
}

__global__ void finalize_kernel(const bf16* __restrict__ h, const float* __restrict__ c,
                                float* __restrict__ out)
{
    int idx = (blockIdx.x * 256 + threadIdx.x) * 4;
    if (idx >= SD * HD) return;
    uint2 hv4 = *(const uint2*)(h + idx);
    const unsigned short* hu = (const unsigned short*)&hv4;
    float4 hf = { bfbits2f(hu[0]), bfbits2f(hu[1]), bfbits2f(hu[2]), bfbits2f(hu[3]) };
    *(float4*)(out + SD + idx) = hf;
    *(float4*)(out + SD + SD * HD + idx) = *(const float4*)(c + idx);
}

// ---------------------------------------------------------------------------
extern "C" void kernel_launch(void* const* d_in, const int* in_sizes, int n_in,
                              void* d_out, int out_size, void* d_ws, size_t ws_size,
                              hipStream_t stream)
{
    (void)in_sizes; (void)n_in; (void)out_size;
    const float* inputDataF = (const float*)d_in[0];
    const float* lane = (const float*)d_in[1];
    const float* Wlg1 = (const float*)d_in[2];
    const float* blg1 = (const float*)d_in[3];
    const float* Wlg2 = (const float*)d_in[4];
    const float* blg2 = (const float*)d_in[5];
    const float* We1 = (const float*)d_in[6];
    const float* be1 = (const float*)d_in[7];
    const float* We2 = (const float*)d_in[8];
    const float* be2 = (const float*)d_in[9];
    const float* Wih = (const float*)d_in[10];
    const float* bih = (const float*)d_in[11];
    const float* Whh = (const float*)d_in[12];
    const float* bhh = (const float*)d_in[13];
    const float* Wout = (const float*)d_in[14];
    const float* bout = (const float*)d_in[15];
    const float* Wf1 = (const float*)d_in[16];
    const float* bf1 = (const float*)d_in[17];
    const float* Wf2 = (const float*)d_in[18];
    const float* bf2 = (const float*)d_in[19];
    const float* Wf3 = (const float*)d_in[20];
    const float* bf3 = (const float*)d_in[21];
    float* out = (float*)d_out;

    char* wp = (char*)d_ws;
    auto carve = [&](size_t bytes) { char* p = wp; wp += (bytes + 255) & ~(size_t)255; return p; };

    bf16* inb   = (bf16*)carve((size_t)SD * TD * ID * 2);
    float* laneCbuf = (float*)carve(2 * sizeof(float));
    float* cbuf0 = (float*)carve((size_t)SD * HD * 4);
    float* cbuf1 = (float*)carve((size_t)SD * HD * 4);
    bf16* hbuf  = (bf16*)carve((size_t)SD * HD * 2);
    bf16* hpA   = (bf16*)carve((size_t)SD * HD * 2);
    bf16* hpB   = (bf16*)carve((size_t)SD * HD * 2);
    bf16* Wpack = (bf16*)carve((size_t)GD * (ED + HD) * 2);
    float* biasg = (float*)carve(GD * 4);
    float* bf2f = (float*)carve(128 * 4);
    bf16* We1b  = (bf16*)carve((size_t)EHD * ID * 2);
    bf16* We2b  = (bf16*)carve((size_t)ED * EHD * 2);
    bf16* Woutb = (bf16*)carve((size_t)OD * HD * 2);
    bf16* Wf1b  = (bf16*)carve((size_t)F1D * OD * 2);
    bf16* Wf2p  = (bf16*)carve((size_t)128 * F1D * 2);
    bf16* out_o = (bf16*)carve((size_t)SD * OD * 2);
    bf16* xf1   = (bf16*)carve((size_t)SD * F1D * 2);
    bf16* xf2   = (bf16*)carve((size_t)SD * F2D * 2);

    const size_t SZ_X1 = (size_t)SD * TD * EHD * 2;
    const size_t SZ_X2 = (size_t)SD * TD * ED * 2;
    const size_t used = (size_t)(wp - (char*)d_ws);
    const size_t remain = (ws_size > used) ? (ws_size - used) : 0;
    const bool persist = remain >= (SZ_X1 + SZ_X2 + 4096);

    bf16* x1 = nullptr; bf16* x2 = nullptr;
    bf16* x1t = nullptr; bf16* x2t = nullptr;
    if (persist) {
        x1 = (bf16*)carve(SZ_X1);
        x2 = (bf16*)carve(SZ_X2);
    } else {
        x1t = (bf16*)carve((size_t)SD * EHD * 2);
        x2t = (bf16*)carve((size_t)SD * ED * 2);
    }

    const int PREP_N = GD * (ED + HD) + GD + EHD * ID + ED * EHD + OD * HD
                     + F1D * OD + 128 * F1D + 128;

    cvt_input_kernel<<<SD * TD * ID / (256 * 8), 256, 0, stream>>>(inputDataF, inb);
    prep_kernel<<<(PREP_N + 255) / 256, 256, 0, stream>>>(
        Wih, Whh, bih, bhh, We1, We2, Wout, Wf1, Wf2, bf2,
        Wpack, biasg, We1b, We2b, Woutb, Wf1b, Wf2p, bf2f);
    lane_kernel<<<1, 64, 0, stream>>>(lane, Wlg1, blg1, Wlg2, blg2, laneCbuf);
    zero_kernel<<<SD * HD / 256, 256, 0, stream>>>(cbuf0, hbuf, hpB);

    bool coop_ok = false;
    if (persist) {
        gemm_kernel<MODE_BF16><<<dim3(SD * TD / 128, 1), 256, 0, stream>>>(
            inb, ID, We1b, ID, be1, laneCbuf, 1, x1, EHD, ID, EHD);
        gemm_kernel<MODE_SCATTER><<<dim3(SD * TD / 128, ED / 128), 256, 0, stream>>>(
            x1, EHD, We2b, EHD, be2, nullptr, 1, x2, ED, EHD, ED);

        void* args[] = { (void*)&x2, (void*)&hpA, (void*)&hpB,
                         (void*)&Wpack, (void*)&biasg, (void*)&cbuf0 };
        hipError_t cerr = hipLaunchCooperativeKernel(
            (const void*)lstm_persistent, dim3(SD / 128, GD / 128), dim3(256),
            args, 0, stream);
        if (cerr == hipSuccess) {
            coop_ok = true;
            // final un-pooled h is in hpB (t=63 odd -> hW=hpB); pool it
            maxpool_kernel<<<SD * HD / (256 * 8), 256, 0, stream>>>(hpB, hbuf);
        }
    }

    if (!coop_ok) {
        // fallback: per-step launches (known-good R4 structure)
        for (int t = 0; t < TD; ++t) {
            const float* c_in = (t & 1) ? cbuf1 : cbuf0;
            float* c_out = (t & 1) ? cbuf0 : cbuf1;
            const bf16* xA;
            if (persist) {
                xA = x2 + (size_t)t * SD * ED;
            } else {
                gemm_kernel<MODE_BF16><<<dim3(SD / 128, 1), 256, 0, stream>>>(
                    inb + (size_t)t * ID, TD * ID, We1b, ID, be1, laneCbuf, 1,
                    x1t, EHD, ID, EHD);
                gemm_kernel<MODE_BF16><<<dim3(SD / 128, ED / 128), 256, 0, stream>>>(
                    x1t, EHD, We2b, EHD, be2, nullptr, 1, x2t, ED, EHD, ED);
                xA = x2t;
            }
            lstm_step<<<dim3(SD / 128, GD / 128), 256, 0, stream>>>(
                xA, hbuf, Wpack, biasg, c_in, c_out, hpA);
            maxpool_kernel<<<SD * HD / (256 * 8), 256, 0, stream>>>(hpA, hbuf);
        }
        // t=63 odd -> final c in cbuf0
    }

    // Output head: pooled h in hbuf, final c in cbuf0 (both paths)
    gemm_kernel<MODE_BF16><<<dim3(SD / 128, 1), 256, 0, stream>>>(
        hbuf, HD, Woutb, HD, bout, nullptr, 0, out_o, OD, HD, OD);
    gemm_kernel<MODE_BF16><<<dim3(SD / 128, F1D / 128), 256, 0, stream>>>(
        out_o, OD, Wf1b, OD, bf1, nullptr, 1, xf1, F1D, OD, F1D);
    gemm_kernel<MODE_BF16><<<dim3(SD / 128, 1), 256, 0, stream>>>(
        xf1, F1D, Wf2p, F1D, bf2f, nullptr, 1, xf2, F2D, F1D, F2D);
    f3_kernel<<<SD / 256, 256, 0, stream>>>(xf2, Wf3, bf3, laneCbuf, out);
    finalize_kernel<<<SD * HD / (256 * 4), 256, 0, stream>>>(hbuf, cbuf0, out);
}